// Round 10
// baseline (171.317 us; speedup 1.0000x reference)
//
#include <hip/hip_runtime.h>
#include <hip/hip_bf16.h>
#include <math.h>

// ---------------------------------------------------------------------------
// FullAttentionEstimator — fully MFMA-based pipeline.
//   k_prep: weight sums + bf16 transposed weights (WT u/v with Wo folded in u;
//           WqT/WkT for projection B-operands).
//   k_proj: q=Q@Wq, k=K@Wk via MFMA + stats + P/R.
//   k_main: S=(k⊙q_i)@W3 via MFMA; LN + gelu + Wo-dot epilogue.
// Lessons encoded (hard-won):
//  * OCCUPANCY KNOB IS RADIOACTIVE: (256,4) spilled (R6), (512,6) forced a
//    40-VGPR cap -> 930MB scratch traffic (R14). Min-waves/EU stays <= 4.
//  * NEVER GIVE ONE BLOCK THE WHOLE CU: R18's 1024-thr block regressed.
//  * shfl-heavy epilogue reductions lose to LDS red2 (R7, R10 regressed).
//  * R15 B2-removal+prefetch: 110->99.2. R16 MFMA-stats: ->93. R17 BAR_LDS
//    (lgkmcnt-only barrier)+ruv->VGPR: ->81.3. R19 dual-dbuf 1-barrier/iter:
//    ->74.8. R20 k_proj 512thr + k_prep 46blk: total 174->166.8; residue
//    (total - k_main = ~94us) barely moved -> mostly harness-fixed
//    (launch gaps + reset memsets + cold iter-0 in the mean). k_proj
//    restructures have bad EV; k_main is the only live lever.
// R21 (this round), all additive micro-opts on the R19 schedule:
//  1) s_setprio(1) around the MFMA cluster (T5): co-resident block pairs sit
//     at different phases -> scheduler can prefer MFMA-phase waves.
//  2) rsL2 epilogue reads hoisted above BAR (stable since P2): epilogue
//     becomes pure VALU, LDS latency hidden under stage+MFMA.
//  3) ru/rv folded into MFMA C-init (acc = {pu+ru...}): -32 VALU/thread-iter
//     from the epilogue; ruF/rvF unpacked per block (+8 VGPR, cap 128 safe).
// ---------------------------------------------------------------------------

#define EPSLN 1e-5f

// workspace layout (float offsets)
#define WS_QP   0            // 1024 x 128 projected q (fp32)
#define WS_KP   131072
#define WS_PU   262144       // Wo-scaled
#define WS_PV   393216
#define WS_RU   524288       // Wo-scaled
#define WS_RV   655360
#define WS_SQ   786432
#define WS_QQ   787456
#define WS_SK   788480
#define WS_KK   789504
#define WS_GUS  790528
#define WS_GVS  790656
#define WS_CU   790784
#define WS_CV   790912
#define WS_WTU  791040       // bf16 [128 h][384 c] = g⊙Wu^T, Wo-scaled
#define WS_WTV  815616       // bf16 [128 h][384 c] = g⊙Wv^T
#define WS_WQT  840192       // bf16 [128 h][1024 d] = Wq^T
#define WS_WKT  905728       // bf16 [128 h][1024 d] = Wk^T
// end 971264 floats = 3.89 MB

typedef __attribute__((ext_vector_type(8))) short short8;
typedef __attribute__((ext_vector_type(4))) float f32x4;

__device__ inline unsigned short f2bf(float x) {
    unsigned u = __builtin_bit_cast(unsigned, x);
    unsigned r = u + 0x7fffu + ((u >> 16) & 1u);
    return (unsigned short)(r >> 16);
}
__device__ inline float b2f_lo(unsigned v) { return __builtin_bit_cast(float, v << 16); }
__device__ inline float b2f_hi(unsigned v) { return __builtin_bit_cast(float, v & 0xffff0000u); }
__device__ inline unsigned pack_bf2(float a, float b) {   // v_cvt_pk_bf16_f32
    __hip_bfloat162 h = __float22bfloat162_rn(make_float2(a, b));
    unsigned r;
    __builtin_memcpy(&r, &h, 4);
    return r;
}
__device__ inline void store8(unsigned short* p, const unsigned short* v) {
    short8 s;
    #pragma unroll
    for (int e = 0; e < 8; ++e) s[e] = (short)v[e];
    *(short8*)p = s;
}
#define GELU_C1 2.3022035f
#define GELU_C2 0.1029431f
__device__ inline float fast_gelu(float v) {
    float ex = __builtin_amdgcn_exp2f(v * fmaf(v * v, GELU_C2, GELU_C1));
    float r  = __builtin_amdgcn_rcpf(ex + 1.f);
    return v - v * r;
}
// LDS-only barrier: orders LDS (lgkmcnt) across the workgroup but leaves
// global loads in flight (no vmcnt drain — unlike __syncthreads()).
#define BAR_LDS() asm volatile("s_waitcnt lgkmcnt(0)\n\ts_barrier" ::: "memory")

// ---------------- kernel 1: weight prep (46 blocks x 256) -----------------
// tasks 0,1: g/bln sums. tasks 2..13: WT u/v transpose, 64-col chunks.
// tasks 14..45: WQT/WKT transpose, 64-col chunks.
__global__ __launch_bounds__(256, 2)
void k_prep(const float* __restrict__ Wu, const float* __restrict__ bu,
            const float* __restrict__ Wv, const float* __restrict__ bv,
            const float* __restrict__ g, const float* __restrict__ bln,
            const float* __restrict__ Wo,
            const float* __restrict__ Wq, const float* __restrict__ Wk,
            float* __restrict__ ws) {
    int task = blockIdx.x, t = threadIdx.x;
    if (task < 2) {
        bool isV = task != 0;
        const float* W  = isV ? Wv : Wu;
        const float* bb = isV ? bv : bu;
        float* gout = ws + (isV ? WS_GVS : WS_GUS);
        float* cout = ws + (isV ? WS_CV : WS_CU);
        __shared__ float rg[2][128], rc[2][128];
        int tl = t & 127, g2 = t >> 7;
        float gu = 0.f, cu = 0.f;
        #pragma unroll 4
        for (int c = g2 * 192; c < g2 * 192 + 192; ++c) {
            float wv_ = W[c * 128 + tl];
            gu += g[c] * wv_;
            cu += bln[c] * wv_;
        }
        rg[g2][tl] = gu; rc[g2][tl] = cu;
        __syncthreads();
        if (t < 128) gout[t] = rg[0][t] + rg[1][t];
        else { int h = t - 128; cout[h] = rc[0][h] + rc[1][h] + bb[h]; }
    } else if (task < 14) {
        int tt = task - 2;
        bool isV = tt >= 6;
        int seg = isV ? tt - 6 : tt;         // 0..5, 64-col chunk of 384
        const float* W = isV ? Wv : Wu;
        unsigned short* wt = (unsigned short*)(ws + (isV ? WS_WTV : WS_WTU));
        __shared__ unsigned short tile[64 * 130];
        #pragma unroll 4
        for (int it = 0; it < 32; ++it) {
            int idx = t + 256 * it;
            int c = idx >> 7, h = idx & 127;
            int cg = seg * 64 + c;
            float s = g[cg] * (isV ? 1.f : Wo[h]);
            tile[c * 130 + h] = f2bf(s * W[cg * 128 + h]);
        }
        __syncthreads();
        int h = t >> 1, c0 = (t & 1) * 32;
        for (int cc = 0; cc < 32; cc += 8) {
            unsigned short v[8];
            #pragma unroll
            for (int e = 0; e < 8; ++e) v[e] = tile[(c0 + cc + e) * 130 + h];
            store8(&wt[h * 384 + seg * 64 + c0 + cc], v);
        }
    } else {
        int tt = task - 14;
        bool isK = tt >= 16;
        int seg = isK ? tt - 16 : tt;        // 0..15, 64-col chunk of 1024
        const float* W = isK ? Wk : Wq;
        unsigned short* wt = (unsigned short*)(ws + (isK ? WS_WKT : WS_WQT));
        __shared__ unsigned short tile[64 * 130];
        #pragma unroll 4
        for (int it = 0; it < 32; ++it) {
            int idx = t + 256 * it;
            int c = idx >> 7, h = idx & 127;
            tile[c * 130 + h] = f2bf(W[(size_t)(seg * 64 + c) * 128 + h]);
        }
        __syncthreads();
        int h = t >> 1, c0 = (t & 1) * 32;
        for (int cc = 0; cc < 32; cc += 8) {
            unsigned short v[8];
            #pragma unroll
            for (int e = 0; e < 8; ++e) v[e] = tile[(c0 + cc + e) * 130 + h];
            store8(&wt[h * 1024 + seg * 64 + c0 + cc], v);
        }
    }
}

// ---------------- kernel 2: MFMA projection + stats + P/R (R20: 512 thr) ---
// 256 blocks x 512 thr / 8 waves; 8 rows/block (blocks 0..127: Q, rest: K).
// Wave w owns h-cols [w*16, w*16+16) for main proj; P/R: uv=w&1, nh=w>>1.
// m-tile rows 8..15 never staged/stored (garbage rows never read).
#define XST 1028   // staged-row stride (shorts)
#define QST 132    // qpL stride (shorts)
__global__ __launch_bounds__(512, 2)
void k_proj(const float* __restrict__ Q, const float* __restrict__ K,
            float* __restrict__ ws) {
    int blk = blockIdx.x, t = threadIdx.x;
    bool isK = blk >= 128;
    int r0 = (blk & 127) * 8;
    const float* src = isK ? K : Q;
    const unsigned short* wtin = (const unsigned short*)(ws + (isK ? WS_WKT : WS_WQT));
    float* dst = ws + (isK ? WS_KP : WS_QP);
    int L = t & 63, w = t >> 6;          // 8 waves
    int col = L & 15, quad = L >> 4;
    int h = w * 16 + col;                // this wave's h-column

    __shared__ unsigned short XLb[16 * XST];
    __shared__ unsigned short qpL[16 * QST];
    __shared__ float sp1[16][8], sp2[16][8];

    {   // stage 8 rows x 1024 d as bf16: 512 thr x 16 cols (exact coverage)
        int srow = t >> 6;               // 0..7
        int c0 = (t & 63) * 16;
        const float* sp = src + (size_t)(r0 + srow) * 1024 + c0;
        unsigned pk[8];
        #pragma unroll
        for (int e4 = 0; e4 < 4; ++e4) {
            float4 xv = *(const float4*)(sp + e4 * 4);
            pk[e4 * 2]     = pack_bf2(xv.x, xv.y);
            pk[e4 * 2 + 1] = pack_bf2(xv.z, xv.w);
        }
        unsigned* xp = (unsigned*)&XLb[srow * XST + c0];
        *(uint4*)&xp[0] = *(uint4*)&pk[0];
        *(uint4*)&xp[4] = *(uint4*)&pk[4];
    }
    __syncthreads();

    f32x4 acc = (f32x4){0.f, 0.f, 0.f, 0.f};
    #pragma unroll 4
    for (int ks = 0; ks < 32; ++ks) {
        short8 a = *(const short8*)&XLb[col * XST + ks * 32 + quad * 8];
        short8 b = *(const short8*)&wtin[(size_t)h * 1024 + ks * 32 + quad * 8];
        acc = __builtin_amdgcn_mfma_f32_16x16x32_bf16(a, b, acc, 0, 0, 0);
    }

    #pragma unroll
    for (int r = 0; r < 4; ++r) {
        int row = quad * 4 + r;
        float s1 = acc[r];
        float s2 = acc[r] * acc[r];
        #pragma unroll
        for (int d = 1; d < 16; d <<= 1) { s1 += __shfl_xor(s1, d); s2 += __shfl_xor(s2, d); }
        if (col == 0) { sp1[row][w] = s1; sp2[row][w] = s2; }
        qpL[row * QST + h] = f2bf(acc[r]);
        if (row < 8) dst[(size_t)(r0 + row) * 128 + h] = acc[r];
    }
    __syncthreads();
    if (t < 8) {
        float a1 = 0.f, a2 = 0.f;
        #pragma unroll
        for (int e = 0; e < 8; ++e) { a1 += sp1[t][e]; a2 += sp2[t][e]; }
        ws[(isK ? WS_SK : WS_SQ) + r0 + t] = a1;
        ws[(isK ? WS_KK : WS_QQ) + r0 + t] = a2;
    }

    int uv = w & 1, nh = w >> 1;         // 8 waves: u/v x 4 h-quarters
    const unsigned short* wt = (const unsigned short*)(ws + (uv ? WS_WTV : WS_WTU));
    int cb0 = isK ? 128 : 0;
    f32x4 pacc[2];
    pacc[0] = (f32x4){0.f, 0.f, 0.f, 0.f};
    pacc[1] = (f32x4){0.f, 0.f, 0.f, 0.f};
    #pragma unroll
    for (int ks = 0; ks < 4; ++ks) {
        short8 a = *(const short8*)&qpL[col * QST + ks * 32 + quad * 8];
        #pragma unroll
        for (int nt = 0; nt < 2; ++nt) {
            int hh = nh * 32 + nt * 16 + col;
            short8 b = *(const short8*)&wt[hh * 384 + cb0 + ks * 32 + quad * 8];
            pacc[nt] = __builtin_amdgcn_mfma_f32_16x16x32_bf16(a, b, pacc[nt], 0, 0, 0);
        }
    }
    float* PO = ws + (uv ? (isK ? WS_RV : WS_PV) : (isK ? WS_RU : WS_PU));
    #pragma unroll
    for (int nt = 0; nt < 2; ++nt)
        #pragma unroll
        for (int r = 0; r < 4; ++r) {
            int row = quad * 4 + r;
            if (row < 8)
                PO[(size_t)(r0 + row) * 128 + nh * 32 + nt * 16 + col] = pacc[nt][r];
        }
}

// ---------------- kernel 3: MFMA main (R21: setprio + hoists on R19) -------
// grid 1024 = 2 b x 32 i-groups(16 i) x 16 j-tiles; 512 thr / 8 waves; wave w
// owns h-cols [w*16, w*16+16). 1 barrier/iter, dual dbuf (Alds + red2).
#define ASTR 152   // bf16 A stride: 76 dw ≡ 12 mod 32, 16B-aligned
#define REDS 132   // red2 row stride (floats), 128 entries/row
#define PST  136   // prologue q/q2/k/k2 tile stride (shorts)
// LDS layout (bytes):
//   Alds0 @0 (9728) | Alds1 @9728 (9728) | red2_0 @19456 (16896)
//   red2_1 @36352 (16896) | rsL2 @53248 (4096)  — total 57344
//   prolog (pre-P2 only, unioned): QL@0 4352; Q2L@4352; KL@8704 8704;
//   K2L@17408 8704  (26112)
__global__ __launch_bounds__(512, 4)
void k_main(const float* __restrict__ ws, float* __restrict__ out,
            const float* __restrict__ Wo, const float* __restrict__ bo) {
    int blk = blockIdx.x;
    int jt = blk & 15, ig = (blk >> 4) & 31, b = blk >> 9;
    int t = threadIdx.x;
    int L = t & 63, w = t >> 6;          // 8 waves
    int col = L & 15, quad = L >> 4;
    int krow0 = b * 512 + jt * 32;
    int jj = t >> 4, cb = (t & 15) * 8;  // staging: row jj, c-range [cb, cb+8)
    int h = w * 16 + col;                // this wave's h-column

    __shared__ __align__(16) char smem[57344];
    unsigned short* Alds0 = (unsigned short*)smem;
    unsigned short* Alds1 = (unsigned short*)(smem + 9728);
    float*          red20 = (float*)(smem + 19456);
    float*          red21 = (float*)(smem + 36352);
    unsigned short* QL    = (unsigned short*)smem;
    unsigned short* Q2L   = (unsigned short*)(smem + 4352);
    unsigned short* KL    = (unsigned short*)(smem + 8704);
    unsigned short* K2L   = (unsigned short*)(smem + 17408);
    float*          rsL2  = (float*)(smem + 53248);

    int bi0 = b * 512 + ig * 16;

    // ---- block-invariant staging ----
    float kreg[8];
    {
        const float* kp = ws + WS_KP + (size_t)(krow0 + jj) * 128 + cb;
        #pragma unroll
        for (int e = 0; e < 8; ++e) kreg[e] = kp[e];
        // bf16 k and k^2 tiles for the stats MFMA
        unsigned kk4[4], k2[4];
        #pragma unroll
        for (int e = 0; e < 4; ++e) {
            kk4[e] = pack_bf2(kreg[e * 2], kreg[e * 2 + 1]);
            k2[e]  = pack_bf2(kreg[e * 2] * kreg[e * 2], kreg[e * 2 + 1] * kreg[e * 2 + 1]);
        }
        *(uint4*)&KL[jj * PST + cb]  = *(uint4*)&kk4[0];
        *(uint4*)&K2L[jj * PST + cb] = *(uint4*)&k2[0];
    }
    {   // q and q^2 tiles: 16 i-rows x 128 c
        int row = t >> 5, c0 = (t & 31) * 4;
        float4 qv = *(const float4*)(ws + WS_QP + (size_t)(bi0 + row) * 128 + c0);
        unsigned q01 = pack_bf2(qv.x, qv.y), q23 = pack_bf2(qv.z, qv.w);
        unsigned s01 = pack_bf2(qv.x * qv.x, qv.y * qv.y);
        unsigned s23 = pack_bf2(qv.z * qv.z, qv.w * qv.w);
        uint2 qp = make_uint2(q01, q23), sp = make_uint2(s01, s23);
        *(uint2*)&QL[row * PST + c0]  = qp;
        *(uint2*)&Q2L[row * PST + c0] = sp;
    }
    // per-thread (ru,rv) unpacked floats — block-invariant (jl, h fixed);
    // folded into the MFMA C-init below (R21 change 3).
    float ruF[8], rvF[8];
    #pragma unroll
    for (int mt = 0; mt < 2; ++mt)
        #pragma unroll
        for (int r = 0; r < 4; ++r) {
            int jl = mt * 16 + quad * 4 + r;
            ruF[mt * 4 + r] = ws[WS_RU + (size_t)(krow0 + jl) * 128 + h];
            rvF[mt * 4 + r] = ws[WS_RV + (size_t)(krow0 + jl) * 128 + h];
        }

    // W3 fragments (c 256..384 of WT) for this wave's 16 h-cols: 32 VGPRs
    short8 w3f[2][4];
    {
        const unsigned short* wtu = (const unsigned short*)(ws + WS_WTU);
        const unsigned short* wtv = (const unsigned short*)(ws + WS_WTV);
        #pragma unroll
        for (int ks = 0; ks < 4; ++ks) {
            w3f[0][ks] = *(const short8*)&wtu[h * 384 + 256 + ks * 32 + quad * 8];
            w3f[1][ks] = *(const short8*)&wtv[h * 384 + 256 + ks * 32 + quad * 8];
        }
    }
    float wo  = Wo[h];
    float gusv = ws[WS_GUS + h] * wo;
    float cuv  = ws[WS_CU + h] * wo;
    float gvsv = ws[WS_GVS + h];
    float cvv  = ws[WS_CV + h];
    float bo0 = bo[0];

    // ---- hoisted prefetch bases (affine in ii) ----
    const float* qpBase = ws + WS_QP + (size_t)bi0 * 128 + cb;
    const float* puBase = ws + WS_PU + (size_t)bi0 * 128 + h;
    const float* pvBase = ws + WS_PV + (size_t)bi0 * 128 + h;
    float4 qA = *(const float4*)(qpBase);
    float4 qB = *(const float4*)(qpBase + 4);
    float puv = puBase[0];
    float pvv = pvBase[0];
    __syncthreads();                                         // P1: QL/Q2L/KL/K2L ready

    // ---- stats via MFMA: d1 = q@k^T, d2 = q^2@(k^2)^T (waves 0,1) ----
    if (w < 2) {
        int j = w * 16 + col;
        f32x4 d1a = (f32x4){0.f, 0.f, 0.f, 0.f};
        f32x4 d2a = (f32x4){0.f, 0.f, 0.f, 0.f};
        #pragma unroll
        for (int ks = 0; ks < 4; ++ks) {
            short8 aq  = *(const short8*)&QL[col * PST + ks * 32 + quad * 8];
            short8 bk  = *(const short8*)&KL[j * PST + ks * 32 + quad * 8];
            d1a = __builtin_amdgcn_mfma_f32_16x16x32_bf16(aq, bk, d1a, 0, 0, 0);
            short8 aq2 = *(const short8*)&Q2L[col * PST + ks * 32 + quad * 8];
            short8 bk2 = *(const short8*)&K2L[j * PST + ks * 32 + quad * 8];
            d2a = __builtin_amdgcn_mfma_f32_16x16x32_bf16(aq2, bk2, d2a, 0, 0, 0);
        }
        float skj = ws[WS_SK + krow0 + j];
        float kkj = ws[WS_KK + krow0 + j];
        #pragma unroll
        for (int r = 0; r < 4; ++r) {
            int i = quad * 4 + r;
            float mu = (ws[WS_SQ + bi0 + i] + skj + d1a[r]) * (1.0f / 384.0f);
            float e2 = (ws[WS_QQ + bi0 + i] + kkj + d2a[r]) * (1.0f / 384.0f);
            float rs = rsqrtf(e2 - mu * mu + EPSLN);
            *(float2*)&rsL2[(i * 32 + j) * 2] = make_float2(rs, rs * mu);
        }
    }
    __syncthreads();                                         // P2: rsL2 ready; QL/KL free

    #pragma unroll 2
    for (int ii = 0; ii < 16; ++ii) {
        unsigned short* Ap = (ii & 1) ? Alds1 : Alds0;       // compile-time (unroll 2)
        float* Rp = (ii & 1) ? red21 : red20;
        float* Rq = (ii & 1) ? red20 : red21;                // previous iter's buffer
        // ---- issue prefetch ii+1 FIRST (affine; stays in flight over BAR_LDS).
        // ii=15 reads row bi0+16: lands in the next ws region (valid, unused).
        float4 qA2 = *(const float4*)(qpBase + (ii + 1) * 128);
        float4 qB2 = *(const float4*)(qpBase + (ii + 1) * 128 + 4);
        float pu2 = puBase[(ii + 1) * 128];
        float pv2 = pvBase[(ii + 1) * 128];
        // ---- hoisted rsL2 reads (stable since P2; no barrier dependency) ----
        float4 s0a = *(const float4*)&rsL2[(ii * 32 + quad * 4) * 2];
        float4 s1a = *(const float4*)&rsL2[(ii * 32 + quad * 4) * 2 + 4];
        float4 s0b = *(const float4*)&rsL2[(ii * 32 + 16 + quad * 4) * 2];
        float4 s1b = *(const float4*)&rsL2[(ii * 32 + 16 + quad * 4) * 2 + 4];
        // ---- stage A[p] = k ⊙ q_i (bf16) ----
        {
            unsigned pk[4];
            float x0 = kreg[0] * qA.x, x1 = kreg[1] * qA.y;
            float x2 = kreg[2] * qA.z, x3 = kreg[3] * qA.w;
            float y0 = kreg[4] * qB.x, y1 = kreg[5] * qB.y;
            float y2 = kreg[6] * qB.z, y3 = kreg[7] * qB.w;
            pk[0] = pack_bf2(x0, x1); pk[1] = pack_bf2(x2, x3);
            pk[2] = pack_bf2(y0, y1); pk[3] = pack_bf2(y2, y3);
            unsigned* arow = (unsigned*)Ap + jj * (ASTR / 2) + cb / 2;
            *(uint4*)&arow[0] = *(uint4*)&pk[0];
        }
        BAR_LDS();                              // B: A[p] ready; red2[p^1] (epi ii-1) done
        // ---- K-loop: S = A @ W3 via MFMA; C init = pu+ru / pv+rv ----
        __builtin_amdgcn_s_setprio(1);
        f32x4 acc[2][2];
        #pragma unroll
        for (int mt = 0; mt < 2; ++mt) {
            acc[mt][0] = (f32x4){puv + ruF[mt * 4 + 0], puv + ruF[mt * 4 + 1],
                                 puv + ruF[mt * 4 + 2], puv + ruF[mt * 4 + 3]};
            acc[mt][1] = (f32x4){pvv + rvF[mt * 4 + 0], pvv + rvF[mt * 4 + 1],
                                 pvv + rvF[mt * 4 + 2], pvv + rvF[mt * 4 + 3]};
        }
        #pragma unroll
        for (int ks = 0; ks < 4; ++ks) {
            short8 a0 = *(const short8*)&Ap[col * ASTR + ks * 32 + quad * 8];
            short8 a1 = *(const short8*)&Ap[(col + 16) * ASTR + ks * 32 + quad * 8];
            acc[0][0] = __builtin_amdgcn_mfma_f32_16x16x32_bf16(a0, w3f[0][ks], acc[0][0], 0, 0, 0);
            acc[0][1] = __builtin_amdgcn_mfma_f32_16x16x32_bf16(a0, w3f[1][ks], acc[0][1], 0, 0, 0);
            acc[1][0] = __builtin_amdgcn_mfma_f32_16x16x32_bf16(a1, w3f[0][ks], acc[1][0], 0, 0, 0);
            acc[1][1] = __builtin_amdgcn_mfma_f32_16x16x32_bf16(a1, w3f[1][ks], acc[1][1], 0, 0, 0);
        }
        __builtin_amdgcn_s_setprio(0);
        // ---- tail for iter ii-1 (reads red2[p^1]; fills MFMA latency shadow) ----
        if (ii > 0 && t < 256) {
            const float4* rr = (const float4*)&Rq[(t >> 3) * REDS];
            int k = t & 7;
            float s = 0.f;
            #pragma unroll
            for (int c4 = 0; c4 < 4; ++c4) {
                float4 x = rr[k + c4 * 8];
                s += (x.x + x.y) + (x.z + x.w);
            }
            s += __shfl_xor(s, 1);
            s += __shfl_xor(s, 2);
            s += __shfl_xor(s, 4);
            if (k == 0)
                out[(size_t)(bi0 + ii - 1) * 512 + jt * 32 + (t >> 3)] = s + bo0;
        }
        // ---- epilogue: u', v, fast-gelu -> red2[p] (pure VALU now) ----
        #pragma unroll
        for (int mt = 0; mt < 2; ++mt) {
            float4 s0 = mt ? s0b : s0a;
            float4 s1 = mt ? s1b : s1a;
            int jb = mt * 16 + quad * 4;
            #pragma unroll
            for (int r = 0; r < 4; ++r) {
                float rs   = r == 0 ? s0.x : r == 1 ? s0.z : r == 2 ? s1.x : s1.z;
                float rsmu = r == 0 ? s0.y : r == 1 ? s0.w : r == 2 ? s1.y : s1.w;
                int jl = jb + r;
                float u   = fmaf(rs, acc[mt][0][r], fmaf(-rsmu, gusv, cuv));
                float v   = fmaf(rs, acc[mt][1][r], fmaf(-rsmu, gvsv, cvv));
                Rp[jl * REDS + w * 16 + col] = u * fast_gelu(v);
            }
        }
        // rotate prefetched state (renamed away by unroll 2)
        qA = qA2; qB = qB2; puv = pu2; pvv = pv2;
    }
    // ---- peeled final tail (iter 15, red2[1]) ----
    BAR_LDS();
    if (t < 256) {
        const float4* rr = (const float4*)&red21[(t >> 3) * REDS];
        int k = t & 7;
        float s = 0.f;
        #pragma unroll
        for (int c4 = 0; c4 < 4; ++c4) {
            float4 x = rr[k + c4 * 8];
            s += (x.x + x.y) + (x.z + x.w);
        }
        s += __shfl_xor(s, 1);
        s += __shfl_xor(s, 2);
        s += __shfl_xor(s, 4);
        if (k == 0)
            out[(size_t)(bi0 + 15) * 512 + jt * 32 + (t >> 3)] = s + bo0;
    }
}

// ---------------------------------------------------------------------------
extern "C" void kernel_launch(void* const* d_in, const int* in_sizes, int n_in,
                              void* d_out, int out_size, void* d_ws, size_t ws_size,
                              hipStream_t stream) {
    const float* Q   = (const float*)d_in[0];
    const float* K   = (const float*)d_in[1];
    const float* Wq  = (const float*)d_in[2];
    const float* Wk  = (const float*)d_in[3];
    const float* g   = (const float*)d_in[4];
    const float* bln = (const float*)d_in[5];
    const float* Wu  = (const float*)d_in[6];
    const float* bu  = (const float*)d_in[7];
    const float* Wv  = (const float*)d_in[8];
    const float* bv  = (const float*)d_in[9];
    const float* Wo  = (const float*)d_in[10];
    const float* bo  = (const float*)d_in[11];
    float* ws  = (float*)d_ws;
    float* out = (float*)d_out;

    hipLaunchKernelGGL(k_prep, dim3(46), dim3(256), 0, stream, Wu, bu, Wv, bv, g, bln, Wo, Wq, Wk, ws);
    hipLaunchKernelGGL(k_proj, dim3(256), dim3(512), 0, stream, Q, K, ws);
    hipLaunchKernelGGL(k_main, dim3(1024), dim3(512), 0, stream, ws, out, Wo, bo);
}

// Round 11
// 169.357 us; speedup vs baseline: 1.0116x; 1.0116x over previous
//
#include <hip/hip_runtime.h>
#include <hip/hip_bf16.h>
#include <math.h>

// ---------------------------------------------------------------------------
// FullAttentionEstimator — fully MFMA-based pipeline.
//   k_prep: weight sums + bf16 transposed weights (WT u/v with Wo folded in u;
//           WqT/WkT for projection B-operands).
//   k_proj: q=Q@Wq, k=K@Wk via MFMA + stats + P/R.
//   k_main: S=(k⊙q_i)@W3 via MFMA; LN + gelu + Wo-dot epilogue.
// Lessons encoded (hard-won):
//  * OCCUPANCY KNOB IS RADIOACTIVE: (256,4) spilled (R6), (512,6) forced a
//    40-VGPR cap -> 930MB scratch traffic (R14). Min-waves/EU stays <= 4.
//  * K_MAIN IS PINNED AT THE 64-VGPR QUANTUM: R21 added ~32 live regs
//    (hoisted rsL2 + ruF/rvF in C-init); compiler kept VGPR=64 and SPILLED
//    (WRITE_SIZE 2048->6300KB, k_main 73->76.7). Any added live-across-MFMA
//    state spills. Epilogue must re-read rsL2 AFTER the barrier; ru/rv stay
//    as packed prR consumed in the epilogue.
//  * NEVER GIVE ONE BLOCK THE WHOLE CU: R18's 1024-thr block regressed.
//  * shfl-heavy epilogue reductions lose to LDS red2 (R7, R10 regressed).
//  * R15 B2-removal+prefetch: 110->99.2. R16 MFMA-stats: ->93. R17 BAR_LDS
//    (lgkmcnt-only barrier)+ruv->VGPR: ->81.3. R19 dual-dbuf 1-barrier/iter:
//    ->74.8. R20 k_proj 512thr + k_prep 46blk: 166.8 total, k_main 73.0.
//    Residue (~94us) is harness-fixed; k_main is the only live lever.
// R22 (this round): k_main = R20 verbatim + ONLY s_setprio(1)/(0) around the
//  MFMA cluster (zero register cost — clean A/B of T5 on the async-2-block
//  structure). If null, controllable levers are exhausted.
// ---------------------------------------------------------------------------

#define EPSLN 1e-5f

// workspace layout (float offsets)
#define WS_QP   0            // 1024 x 128 projected q (fp32)
#define WS_KP   131072
#define WS_PU   262144       // Wo-scaled
#define WS_PV   393216
#define WS_RU   524288       // Wo-scaled
#define WS_RV   655360
#define WS_SQ   786432
#define WS_QQ   787456
#define WS_SK   788480
#define WS_KK   789504
#define WS_GUS  790528
#define WS_GVS  790656
#define WS_CU   790784
#define WS_CV   790912
#define WS_WTU  791040       // bf16 [128 h][384 c] = g⊙Wu^T, Wo-scaled
#define WS_WTV  815616       // bf16 [128 h][384 c] = g⊙Wv^T
#define WS_WQT  840192       // bf16 [128 h][1024 d] = Wq^T
#define WS_WKT  905728       // bf16 [128 h][1024 d] = Wk^T
// end 971264 floats = 3.89 MB

typedef __attribute__((ext_vector_type(8))) short short8;
typedef __attribute__((ext_vector_type(4))) float f32x4;

__device__ inline unsigned short f2bf(float x) {
    unsigned u = __builtin_bit_cast(unsigned, x);
    unsigned r = u + 0x7fffu + ((u >> 16) & 1u);
    return (unsigned short)(r >> 16);
}
__device__ inline float b2f_lo(unsigned v) { return __builtin_bit_cast(float, v << 16); }
__device__ inline float b2f_hi(unsigned v) { return __builtin_bit_cast(float, v & 0xffff0000u); }
__device__ inline unsigned pack_bf2(float a, float b) {   // v_cvt_pk_bf16_f32
    __hip_bfloat162 h = __float22bfloat162_rn(make_float2(a, b));
    unsigned r;
    __builtin_memcpy(&r, &h, 4);
    return r;
}
__device__ inline void store8(unsigned short* p, const unsigned short* v) {
    short8 s;
    #pragma unroll
    for (int e = 0; e < 8; ++e) s[e] = (short)v[e];
    *(short8*)p = s;
}
#define GELU_C1 2.3022035f
#define GELU_C2 0.1029431f
__device__ inline float fast_gelu(float v) {
    float ex = __builtin_amdgcn_exp2f(v * fmaf(v * v, GELU_C2, GELU_C1));
    float r  = __builtin_amdgcn_rcpf(ex + 1.f);
    return v - v * r;
}
// LDS-only barrier: orders LDS (lgkmcnt) across the workgroup but leaves
// global loads in flight (no vmcnt drain — unlike __syncthreads()).
#define BAR_LDS() asm volatile("s_waitcnt lgkmcnt(0)\n\ts_barrier" ::: "memory")

// ---------------- kernel 1: weight prep (46 blocks x 256) -----------------
// tasks 0,1: g/bln sums. tasks 2..13: WT u/v transpose, 64-col chunks.
// tasks 14..45: WQT/WKT transpose, 64-col chunks.
__global__ __launch_bounds__(256, 2)
void k_prep(const float* __restrict__ Wu, const float* __restrict__ bu,
            const float* __restrict__ Wv, const float* __restrict__ bv,
            const float* __restrict__ g, const float* __restrict__ bln,
            const float* __restrict__ Wo,
            const float* __restrict__ Wq, const float* __restrict__ Wk,
            float* __restrict__ ws) {
    int task = blockIdx.x, t = threadIdx.x;
    if (task < 2) {
        bool isV = task != 0;
        const float* W  = isV ? Wv : Wu;
        const float* bb = isV ? bv : bu;
        float* gout = ws + (isV ? WS_GVS : WS_GUS);
        float* cout = ws + (isV ? WS_CV : WS_CU);
        __shared__ float rg[2][128], rc[2][128];
        int tl = t & 127, g2 = t >> 7;
        float gu = 0.f, cu = 0.f;
        #pragma unroll 4
        for (int c = g2 * 192; c < g2 * 192 + 192; ++c) {
            float wv_ = W[c * 128 + tl];
            gu += g[c] * wv_;
            cu += bln[c] * wv_;
        }
        rg[g2][tl] = gu; rc[g2][tl] = cu;
        __syncthreads();
        if (t < 128) gout[t] = rg[0][t] + rg[1][t];
        else { int h = t - 128; cout[h] = rc[0][h] + rc[1][h] + bb[h]; }
    } else if (task < 14) {
        int tt = task - 2;
        bool isV = tt >= 6;
        int seg = isV ? tt - 6 : tt;         // 0..5, 64-col chunk of 384
        const float* W = isV ? Wv : Wu;
        unsigned short* wt = (unsigned short*)(ws + (isV ? WS_WTV : WS_WTU));
        __shared__ unsigned short tile[64 * 130];
        #pragma unroll 4
        for (int it = 0; it < 32; ++it) {
            int idx = t + 256 * it;
            int c = idx >> 7, h = idx & 127;
            int cg = seg * 64 + c;
            float s = g[cg] * (isV ? 1.f : Wo[h]);
            tile[c * 130 + h] = f2bf(s * W[cg * 128 + h]);
        }
        __syncthreads();
        int h = t >> 1, c0 = (t & 1) * 32;
        for (int cc = 0; cc < 32; cc += 8) {
            unsigned short v[8];
            #pragma unroll
            for (int e = 0; e < 8; ++e) v[e] = tile[(c0 + cc + e) * 130 + h];
            store8(&wt[h * 384 + seg * 64 + c0 + cc], v);
        }
    } else {
        int tt = task - 14;
        bool isK = tt >= 16;
        int seg = isK ? tt - 16 : tt;        // 0..15, 64-col chunk of 1024
        const float* W = isK ? Wk : Wq;
        unsigned short* wt = (unsigned short*)(ws + (isK ? WS_WKT : WS_WQT));
        __shared__ unsigned short tile[64 * 130];
        #pragma unroll 4
        for (int it = 0; it < 32; ++it) {
            int idx = t + 256 * it;
            int c = idx >> 7, h = idx & 127;
            tile[c * 130 + h] = f2bf(W[(size_t)(seg * 64 + c) * 128 + h]);
        }
        __syncthreads();
        int h = t >> 1, c0 = (t & 1) * 32;
        for (int cc = 0; cc < 32; cc += 8) {
            unsigned short v[8];
            #pragma unroll
            for (int e = 0; e < 8; ++e) v[e] = tile[(c0 + cc + e) * 130 + h];
            store8(&wt[h * 1024 + seg * 64 + c0 + cc], v);
        }
    }
}

// ---------------- kernel 2: MFMA projection + stats + P/R (R20: 512 thr) ---
// 256 blocks x 512 thr / 8 waves; 8 rows/block (blocks 0..127: Q, rest: K).
// Wave w owns h-cols [w*16, w*16+16) for main proj; P/R: uv=w&1, nh=w>>1.
// m-tile rows 8..15 never staged/stored (garbage rows never read).
#define XST 1028   // staged-row stride (shorts)
#define QST 132    // qpL stride (shorts)
__global__ __launch_bounds__(512, 2)
void k_proj(const float* __restrict__ Q, const float* __restrict__ K,
            float* __restrict__ ws) {
    int blk = blockIdx.x, t = threadIdx.x;
    bool isK = blk >= 128;
    int r0 = (blk & 127) * 8;
    const float* src = isK ? K : Q;
    const unsigned short* wtin = (const unsigned short*)(ws + (isK ? WS_WKT : WS_WQT));
    float* dst = ws + (isK ? WS_KP : WS_QP);
    int L = t & 63, w = t >> 6;          // 8 waves
    int col = L & 15, quad = L >> 4;
    int h = w * 16 + col;                // this wave's h-column

    __shared__ unsigned short XLb[16 * XST];
    __shared__ unsigned short qpL[16 * QST];
    __shared__ float sp1[16][8], sp2[16][8];

    {   // stage 8 rows x 1024 d as bf16: 512 thr x 16 cols (exact coverage)
        int srow = t >> 6;               // 0..7
        int c0 = (t & 63) * 16;
        const float* sp = src + (size_t)(r0 + srow) * 1024 + c0;
        unsigned pk[8];
        #pragma unroll
        for (int e4 = 0; e4 < 4; ++e4) {
            float4 xv = *(const float4*)(sp + e4 * 4);
            pk[e4 * 2]     = pack_bf2(xv.x, xv.y);
            pk[e4 * 2 + 1] = pack_bf2(xv.z, xv.w);
        }
        unsigned* xp = (unsigned*)&XLb[srow * XST + c0];
        *(uint4*)&xp[0] = *(uint4*)&pk[0];
        *(uint4*)&xp[4] = *(uint4*)&pk[4];
    }
    __syncthreads();

    f32x4 acc = (f32x4){0.f, 0.f, 0.f, 0.f};
    #pragma unroll 4
    for (int ks = 0; ks < 32; ++ks) {
        short8 a = *(const short8*)&XLb[col * XST + ks * 32 + quad * 8];
        short8 b = *(const short8*)&wtin[(size_t)h * 1024 + ks * 32 + quad * 8];
        acc = __builtin_amdgcn_mfma_f32_16x16x32_bf16(a, b, acc, 0, 0, 0);
    }

    #pragma unroll
    for (int r = 0; r < 4; ++r) {
        int row = quad * 4 + r;
        float s1 = acc[r];
        float s2 = acc[r] * acc[r];
        #pragma unroll
        for (int d = 1; d < 16; d <<= 1) { s1 += __shfl_xor(s1, d); s2 += __shfl_xor(s2, d); }
        if (col == 0) { sp1[row][w] = s1; sp2[row][w] = s2; }
        qpL[row * QST + h] = f2bf(acc[r]);
        if (row < 8) dst[(size_t)(r0 + row) * 128 + h] = acc[r];
    }
    __syncthreads();
    if (t < 8) {
        float a1 = 0.f, a2 = 0.f;
        #pragma unroll
        for (int e = 0; e < 8; ++e) { a1 += sp1[t][e]; a2 += sp2[t][e]; }
        ws[(isK ? WS_SK : WS_SQ) + r0 + t] = a1;
        ws[(isK ? WS_KK : WS_QQ) + r0 + t] = a2;
    }

    int uv = w & 1, nh = w >> 1;         // 8 waves: u/v x 4 h-quarters
    const unsigned short* wt = (const unsigned short*)(ws + (uv ? WS_WTV : WS_WTU));
    int cb0 = isK ? 128 : 0;
    f32x4 pacc[2];
    pacc[0] = (f32x4){0.f, 0.f, 0.f, 0.f};
    pacc[1] = (f32x4){0.f, 0.f, 0.f, 0.f};
    #pragma unroll
    for (int ks = 0; ks < 4; ++ks) {
        short8 a = *(const short8*)&qpL[col * QST + ks * 32 + quad * 8];
        #pragma unroll
        for (int nt = 0; nt < 2; ++nt) {
            int hh = nh * 32 + nt * 16 + col;
            short8 b = *(const short8*)&wt[hh * 384 + cb0 + ks * 32 + quad * 8];
            pacc[nt] = __builtin_amdgcn_mfma_f32_16x16x32_bf16(a, b, pacc[nt], 0, 0, 0);
        }
    }
    float* PO = ws + (uv ? (isK ? WS_RV : WS_PV) : (isK ? WS_RU : WS_PU));
    #pragma unroll
    for (int nt = 0; nt < 2; ++nt)
        #pragma unroll
        for (int r = 0; r < 4; ++r) {
            int row = quad * 4 + r;
            if (row < 8)
                PO[(size_t)(r0 + row) * 128 + nh * 32 + nt * 16 + col] = pacc[nt][r];
        }
}

// ---------------- kernel 3: MFMA main (R22: R19/R20 + setprio only) --------
// grid 1024 = 2 b x 32 i-groups(16 i) x 16 j-tiles; 512 thr / 8 waves; wave w
// owns h-cols [w*16, w*16+16). 1 barrier/iter, dual dbuf (Alds + red2).
#define ASTR 152   // bf16 A stride: 76 dw ≡ 12 mod 32, 16B-aligned
#define REDS 132   // red2 row stride (floats), 128 entries/row
#define PST  136   // prologue q/q2/k/k2 tile stride (shorts)
// LDS layout (bytes):
//   Alds0 @0 (9728) | Alds1 @9728 (9728) | red2_0 @19456 (16896)
//   red2_1 @36352 (16896) | rsL2 @53248 (4096)  — total 57344
//   prolog (pre-P2 only, unioned): QL@0 4352; Q2L@4352; KL@8704 8704;
//   K2L@17408 8704  (26112)
__global__ __launch_bounds__(512, 4)
void k_main(const float* __restrict__ ws, float* __restrict__ out,
            const float* __restrict__ Wo, const float* __restrict__ bo) {
    int blk = blockIdx.x;
    int jt = blk & 15, ig = (blk >> 4) & 31, b = blk >> 9;
    int t = threadIdx.x;
    int L = t & 63, w = t >> 6;          // 8 waves
    int col = L & 15, quad = L >> 4;
    int krow0 = b * 512 + jt * 32;
    int jj = t >> 4, cb = (t & 15) * 8;  // staging: row jj, c-range [cb, cb+8)
    int h = w * 16 + col;                // this wave's h-column

    __shared__ __align__(16) char smem[57344];
    unsigned short* Alds0 = (unsigned short*)smem;
    unsigned short* Alds1 = (unsigned short*)(smem + 9728);
    float*          red20 = (float*)(smem + 19456);
    float*          red21 = (float*)(smem + 36352);
    unsigned short* QL    = (unsigned short*)smem;
    unsigned short* Q2L   = (unsigned short*)(smem + 4352);
    unsigned short* KL    = (unsigned short*)(smem + 8704);
    unsigned short* K2L   = (unsigned short*)(smem + 17408);
    float*          rsL2  = (float*)(smem + 53248);

    int bi0 = b * 512 + ig * 16;

    // ---- block-invariant staging ----
    float kreg[8];
    {
        const float* kp = ws + WS_KP + (size_t)(krow0 + jj) * 128 + cb;
        #pragma unroll
        for (int e = 0; e < 8; ++e) kreg[e] = kp[e];
        // bf16 k and k^2 tiles for the stats MFMA
        unsigned kk4[4], k2[4];
        #pragma unroll
        for (int e = 0; e < 4; ++e) {
            kk4[e] = pack_bf2(kreg[e * 2], kreg[e * 2 + 1]);
            k2[e]  = pack_bf2(kreg[e * 2] * kreg[e * 2], kreg[e * 2 + 1] * kreg[e * 2 + 1]);
        }
        *(uint4*)&KL[jj * PST + cb]  = *(uint4*)&kk4[0];
        *(uint4*)&K2L[jj * PST + cb] = *(uint4*)&k2[0];
    }
    {   // q and q^2 tiles: 16 i-rows x 128 c
        int row = t >> 5, c0 = (t & 31) * 4;
        float4 qv = *(const float4*)(ws + WS_QP + (size_t)(bi0 + row) * 128 + c0);
        unsigned q01 = pack_bf2(qv.x, qv.y), q23 = pack_bf2(qv.z, qv.w);
        unsigned s01 = pack_bf2(qv.x * qv.x, qv.y * qv.y);
        unsigned s23 = pack_bf2(qv.z * qv.z, qv.w * qv.w);
        uint2 qp = make_uint2(q01, q23), sp = make_uint2(s01, s23);
        *(uint2*)&QL[row * PST + c0]  = qp;
        *(uint2*)&Q2L[row * PST + c0] = sp;
    }
    // per-thread (ru,rv) packed registers — block-invariant (jl, h fixed)
    unsigned prR[8];
    #pragma unroll
    for (int mt = 0; mt < 2; ++mt)
        #pragma unroll
        for (int r = 0; r < 4; ++r) {
            int jl = mt * 16 + quad * 4 + r;
            float ru = ws[WS_RU + (size_t)(krow0 + jl) * 128 + h];
            float rv = ws[WS_RV + (size_t)(krow0 + jl) * 128 + h];
            prR[mt * 4 + r] = pack_bf2(ru, rv);
        }

    // W3 fragments (c 256..384 of WT) for this wave's 16 h-cols: 32 VGPRs
    short8 w3f[2][4];
    {
        const unsigned short* wtu = (const unsigned short*)(ws + WS_WTU);
        const unsigned short* wtv = (const unsigned short*)(ws + WS_WTV);
        #pragma unroll
        for (int ks = 0; ks < 4; ++ks) {
            w3f[0][ks] = *(const short8*)&wtu[h * 384 + 256 + ks * 32 + quad * 8];
            w3f[1][ks] = *(const short8*)&wtv[h * 384 + 256 + ks * 32 + quad * 8];
        }
    }
    float wo  = Wo[h];
    float gusv = ws[WS_GUS + h] * wo;
    float cuv  = ws[WS_CU + h] * wo;
    float gvsv = ws[WS_GVS + h];
    float cvv  = ws[WS_CV + h];
    float bo0 = bo[0];

    // ---- hoisted prefetch bases (affine in ii) ----
    const float* qpBase = ws + WS_QP + (size_t)bi0 * 128 + cb;
    const float* puBase = ws + WS_PU + (size_t)bi0 * 128 + h;
    const float* pvBase = ws + WS_PV + (size_t)bi0 * 128 + h;
    float4 qA = *(const float4*)(qpBase);
    float4 qB = *(const float4*)(qpBase + 4);
    float puv = puBase[0];
    float pvv = pvBase[0];
    __syncthreads();                                         // P1: QL/Q2L/KL/K2L ready

    // ---- stats via MFMA: d1 = q@k^T, d2 = q^2@(k^2)^T (waves 0,1) ----
    if (w < 2) {
        int j = w * 16 + col;
        f32x4 d1a = (f32x4){0.f, 0.f, 0.f, 0.f};
        f32x4 d2a = (f32x4){0.f, 0.f, 0.f, 0.f};
        #pragma unroll
        for (int ks = 0; ks < 4; ++ks) {
            short8 aq  = *(const short8*)&QL[col * PST + ks * 32 + quad * 8];
            short8 bk  = *(const short8*)&KL[j * PST + ks * 32 + quad * 8];
            d1a = __builtin_amdgcn_mfma_f32_16x16x32_bf16(aq, bk, d1a, 0, 0, 0);
            short8 aq2 = *(const short8*)&Q2L[col * PST + ks * 32 + quad * 8];
            short8 bk2 = *(const short8*)&K2L[j * PST + ks * 32 + quad * 8];
            d2a = __builtin_amdgcn_mfma_f32_16x16x32_bf16(aq2, bk2, d2a, 0, 0, 0);
        }
        float skj = ws[WS_SK + krow0 + j];
        float kkj = ws[WS_KK + krow0 + j];
        #pragma unroll
        for (int r = 0; r < 4; ++r) {
            int i = quad * 4 + r;
            float mu = (ws[WS_SQ + bi0 + i] + skj + d1a[r]) * (1.0f / 384.0f);
            float e2 = (ws[WS_QQ + bi0 + i] + kkj + d2a[r]) * (1.0f / 384.0f);
            float rs = rsqrtf(e2 - mu * mu + EPSLN);
            *(float2*)&rsL2[(i * 32 + j) * 2] = make_float2(rs, rs * mu);
        }
    }
    __syncthreads();                                         // P2: rsL2 ready; QL/KL free

    #pragma unroll 2
    for (int ii = 0; ii < 16; ++ii) {
        unsigned short* Ap = (ii & 1) ? Alds1 : Alds0;       // compile-time (unroll 2)
        float* Rp = (ii & 1) ? red21 : red20;
        float* Rq = (ii & 1) ? red20 : red21;                // previous iter's buffer
        // ---- issue prefetch ii+1 FIRST (affine; stays in flight over BAR_LDS).
        // ii=15 reads row bi0+16: lands in the next ws region (valid, unused).
        float4 qA2 = *(const float4*)(qpBase + (ii + 1) * 128);
        float4 qB2 = *(const float4*)(qpBase + (ii + 1) * 128 + 4);
        float pu2 = puBase[(ii + 1) * 128];
        float pv2 = pvBase[(ii + 1) * 128];
        // ---- stage A[p] = k ⊙ q_i (bf16) ----
        {
            unsigned pk[4];
            float x0 = kreg[0] * qA.x, x1 = kreg[1] * qA.y;
            float x2 = kreg[2] * qA.z, x3 = kreg[3] * qA.w;
            float y0 = kreg[4] * qB.x, y1 = kreg[5] * qB.y;
            float y2 = kreg[6] * qB.z, y3 = kreg[7] * qB.w;
            pk[0] = pack_bf2(x0, x1); pk[1] = pack_bf2(x2, x3);
            pk[2] = pack_bf2(y0, y1); pk[3] = pack_bf2(y2, y3);
            unsigned* arow = (unsigned*)Ap + jj * (ASTR / 2) + cb / 2;
            *(uint4*)&arow[0] = *(uint4*)&pk[0];
        }
        BAR_LDS();                              // B: A[p] ready; red2[p^1] (epi ii-1) done
        // ---- K-loop: S = A @ W3 via MFMA; C init = pu/pv (folds the adds) ----
        __builtin_amdgcn_s_setprio(1);
        f32x4 acc[2][2];
        #pragma unroll
        for (int mt = 0; mt < 2; ++mt) {
            acc[mt][0] = (f32x4){puv, puv, puv, puv};
            acc[mt][1] = (f32x4){pvv, pvv, pvv, pvv};
        }
        #pragma unroll
        for (int ks = 0; ks < 4; ++ks) {
            short8 a0 = *(const short8*)&Ap[col * ASTR + ks * 32 + quad * 8];
            short8 a1 = *(const short8*)&Ap[(col + 16) * ASTR + ks * 32 + quad * 8];
            acc[0][0] = __builtin_amdgcn_mfma_f32_16x16x32_bf16(a0, w3f[0][ks], acc[0][0], 0, 0, 0);
            acc[0][1] = __builtin_amdgcn_mfma_f32_16x16x32_bf16(a0, w3f[1][ks], acc[0][1], 0, 0, 0);
            acc[1][0] = __builtin_amdgcn_mfma_f32_16x16x32_bf16(a1, w3f[0][ks], acc[1][0], 0, 0, 0);
            acc[1][1] = __builtin_amdgcn_mfma_f32_16x16x32_bf16(a1, w3f[1][ks], acc[1][1], 0, 0, 0);
        }
        __builtin_amdgcn_s_setprio(0);
        // ---- tail for iter ii-1 (reads red2[p^1]; fills MFMA latency shadow) ----
        if (ii > 0 && t < 256) {
            const float4* rr = (const float4*)&Rq[(t >> 3) * REDS];
            int k = t & 7;
            float s = 0.f;
            #pragma unroll
            for (int c4 = 0; c4 < 4; ++c4) {
                float4 x = rr[k + c4 * 8];
                s += (x.x + x.y) + (x.z + x.w);
            }
            s += __shfl_xor(s, 1);
            s += __shfl_xor(s, 2);
            s += __shfl_xor(s, 4);
            if (k == 0)
                out[(size_t)(bi0 + ii - 1) * 512 + jt * 32 + (t >> 3)] = s + bo0;
        }
        // ---- epilogue: u', v, fast-gelu -> red2[p] ----
        #pragma unroll
        for (int mt = 0; mt < 2; ++mt) {
            int jb = mt * 16 + quad * 4;
            float4 s0 = *(const float4*)&rsL2[(ii * 32 + jb) * 2];
            float4 s1 = *(const float4*)&rsL2[(ii * 32 + jb) * 2 + 4];
            #pragma unroll
            for (int r = 0; r < 4; ++r) {
                float rs   = r == 0 ? s0.x : r == 1 ? s0.z : r == 2 ? s1.x : s1.z;
                float rsmu = r == 0 ? s0.y : r == 1 ? s0.w : r == 2 ? s1.y : s1.w;
                int jl = jb + r;
                unsigned pr = prR[mt * 4 + r];
                float su  = acc[mt][0][r] + b2f_lo(pr);      // acc already includes pu
                float u   = fmaf(rs, su, fmaf(-rsmu, gusv, cuv));
                float sv_ = acc[mt][1][r] + b2f_hi(pr);      // acc already includes pv
                float v   = fmaf(rs, sv_, fmaf(-rsmu, gvsv, cvv));
                Rp[jl * REDS + w * 16 + col] = u * fast_gelu(v);
            }
        }
        // rotate prefetched state (renamed away by unroll 2)
        qA = qA2; qB = qB2; puv = pu2; pvv = pv2;
    }
    // ---- peeled final tail (iter 15, red2[1]) ----
    BAR_LDS();
    if (t < 256) {
        const float4* rr = (const float4*)&red21[(t >> 3) * REDS];
        int k = t & 7;
        float s = 0.f;
        #pragma unroll
        for (int c4 = 0; c4 < 4; ++c4) {
            float4 x = rr[k + c4 * 8];
            s += (x.x + x.y) + (x.z + x.w);
        }
        s += __shfl_xor(s, 1);
        s += __shfl_xor(s, 2);
        s += __shfl_xor(s, 4);
        if (k == 0)
            out[(size_t)(bi0 + 15) * 512 + jt * 32 + (t >> 3)] = s + bo0;
    }
}

// ---------------------------------------------------------------------------
extern "C" void kernel_launch(void* const* d_in, const int* in_sizes, int n_in,
                              void* d_out, int out_size, void* d_ws, size_t ws_size,
                              hipStream_t stream) {
    const float* Q   = (const float*)d_in[0];
    const float* K   = (const float*)d_in[1];
    const float* Wq  = (const float*)d_in[2];
    const float* Wk  = (const float*)d_in[3];
    const float* g   = (const float*)d_in[4];
    const float* bln = (const float*)d_in[5];
    const float* Wu  = (const float*)d_in[6];
    const float* bu  = (const float*)d_in[7];
    const float* Wv  = (const float*)d_in[8];
    const float* bv  = (const float*)d_in[9];
    const float* Wo  = (const float*)d_in[10];
    const float* bo  = (const float*)d_in[11];
    float* ws  = (float*)d_ws;
    float* out = (float*)d_out;

    hipLaunchKernelGGL(k_prep, dim3(46), dim3(256), 0, stream, Wu, bu, Wv, bv, g, bln, Wo, Wq, Wk, ws);
    hipLaunchKernelGGL(k_proj, dim3(256), dim3(512), 0, stream, Q, K, ws);
    hipLaunchKernelGGL(k_main, dim3(1024), dim3(512), 0, stream, ws, out, Wo, bo);
}

// Round 12
// 166.055 us; speedup vs baseline: 1.0317x; 1.0199x over previous
//
#include <hip/hip_runtime.h>
#include <hip/hip_bf16.h>
#include <math.h>

// ---------------------------------------------------------------------------
// FullAttentionEstimator — fully MFMA-based pipeline.
//   k_prep: weight sums + bf16 transposed weights (WT u/v with Wo folded in u;
//           WqT/WkT for projection B-operands).
//   k_proj: q=Q@Wq, k=K@Wk via MFMA + stats + P/R.
//   k_main: S=(k⊙q_i)@W3 via MFMA; LN + gelu + Wo-dot epilogue.
// Lessons encoded (hard-won):
//  * OCCUPANCY KNOB IS RADIOACTIVE: (256,4) spilled (R6), (512,6) forced a
//    40-VGPR cap -> 930MB scratch traffic (R14). Min-waves/EU stays <= 4.
//  * K_MAIN IS PINNED AT THE 64-VGPR QUANTUM: R21 added ~32 live regs;
//    compiler kept VGPR=64 and SPILLED (WRITE 2048->6300KB, 73->76.7).
//    Any added live-across-MFMA state spills.
//  * NEVER GIVE ONE BLOCK THE WHOLE CU: R18's 1024-thr block regressed.
//  * T5 setprio: NULL on this structure (R22: 73.7 vs 73.0 base).
//  * shfl-heavy epilogue reductions lose to LDS red2 (R7, R10 regressed).
//  * R15 B2-removal+prefetch: 110->99.2. R16 MFMA-stats: ->93. R17 BAR_LDS
//    +ruv->VGPR: ->81.3. R19 dual-dbuf 1-barrier/iter: ->74.8. R20 k_proj
//    512thr + k_prep 46blk: total 166.8, k_main 73.0. Residue harness-fixed.
// R23 (this round): amortize per-block fixed costs 2x — i-group 16->32,
//  grid 512 (= exactly 2 blocks/CU, single residency round). Loop body,
//  registers, sync structure byte-identical; rsL2/QL/Q2L double (LDS 61440,
//  still 2 blk/CU); stats prologue now 4 waves (idle fraction halves);
//  block-invariant staging loads halve across the dispatch (watch FETCH_SIZE
//  ~7.3 -> ~6 MB). If null -> structural local minimum, declare.
// ---------------------------------------------------------------------------

#define EPSLN 1e-5f

// workspace layout (float offsets)
#define WS_QP   0            // 1024 x 128 projected q (fp32)
#define WS_KP   131072
#define WS_PU   262144       // Wo-scaled
#define WS_PV   393216
#define WS_RU   524288       // Wo-scaled
#define WS_RV   655360
#define WS_SQ   786432
#define WS_QQ   787456
#define WS_SK   788480
#define WS_KK   789504
#define WS_GUS  790528
#define WS_GVS  790656
#define WS_CU   790784
#define WS_CV   790912
#define WS_WTU  791040       // bf16 [128 h][384 c] = g⊙Wu^T, Wo-scaled
#define WS_WTV  815616       // bf16 [128 h][384 c] = g⊙Wv^T
#define WS_WQT  840192       // bf16 [128 h][1024 d] = Wq^T
#define WS_WKT  905728       // bf16 [128 h][1024 d] = Wk^T
// end 971264 floats = 3.89 MB

typedef __attribute__((ext_vector_type(8))) short short8;
typedef __attribute__((ext_vector_type(4))) float f32x4;

__device__ inline unsigned short f2bf(float x) {
    unsigned u = __builtin_bit_cast(unsigned, x);
    unsigned r = u + 0x7fffu + ((u >> 16) & 1u);
    return (unsigned short)(r >> 16);
}
__device__ inline float b2f_lo(unsigned v) { return __builtin_bit_cast(float, v << 16); }
__device__ inline float b2f_hi(unsigned v) { return __builtin_bit_cast(float, v & 0xffff0000u); }
__device__ inline unsigned pack_bf2(float a, float b) {   // v_cvt_pk_bf16_f32
    __hip_bfloat162 h = __float22bfloat162_rn(make_float2(a, b));
    unsigned r;
    __builtin_memcpy(&r, &h, 4);
    return r;
}
__device__ inline void store8(unsigned short* p, const unsigned short* v) {
    short8 s;
    #pragma unroll
    for (int e = 0; e < 8; ++e) s[e] = (short)v[e];
    *(short8*)p = s;
}
#define GELU_C1 2.3022035f
#define GELU_C2 0.1029431f
__device__ inline float fast_gelu(float v) {
    float ex = __builtin_amdgcn_exp2f(v * fmaf(v * v, GELU_C2, GELU_C1));
    float r  = __builtin_amdgcn_rcpf(ex + 1.f);
    return v - v * r;
}
// LDS-only barrier: orders LDS (lgkmcnt) across the workgroup but leaves
// global loads in flight (no vmcnt drain — unlike __syncthreads()).
#define BAR_LDS() asm volatile("s_waitcnt lgkmcnt(0)\n\ts_barrier" ::: "memory")

// ---------------- kernel 1: weight prep (46 blocks x 256) -----------------
// tasks 0,1: g/bln sums. tasks 2..13: WT u/v transpose, 64-col chunks.
// tasks 14..45: WQT/WKT transpose, 64-col chunks.
__global__ __launch_bounds__(256, 2)
void k_prep(const float* __restrict__ Wu, const float* __restrict__ bu,
            const float* __restrict__ Wv, const float* __restrict__ bv,
            const float* __restrict__ g, const float* __restrict__ bln,
            const float* __restrict__ Wo,
            const float* __restrict__ Wq, const float* __restrict__ Wk,
            float* __restrict__ ws) {
    int task = blockIdx.x, t = threadIdx.x;
    if (task < 2) {
        bool isV = task != 0;
        const float* W  = isV ? Wv : Wu;
        const float* bb = isV ? bv : bu;
        float* gout = ws + (isV ? WS_GVS : WS_GUS);
        float* cout = ws + (isV ? WS_CV : WS_CU);
        __shared__ float rg[2][128], rc[2][128];
        int tl = t & 127, g2 = t >> 7;
        float gu = 0.f, cu = 0.f;
        #pragma unroll 4
        for (int c = g2 * 192; c < g2 * 192 + 192; ++c) {
            float wv_ = W[c * 128 + tl];
            gu += g[c] * wv_;
            cu += bln[c] * wv_;
        }
        rg[g2][tl] = gu; rc[g2][tl] = cu;
        __syncthreads();
        if (t < 128) gout[t] = rg[0][t] + rg[1][t];
        else { int h = t - 128; cout[h] = rc[0][h] + rc[1][h] + bb[h]; }
    } else if (task < 14) {
        int tt = task - 2;
        bool isV = tt >= 6;
        int seg = isV ? tt - 6 : tt;         // 0..5, 64-col chunk of 384
        const float* W = isV ? Wv : Wu;
        unsigned short* wt = (unsigned short*)(ws + (isV ? WS_WTV : WS_WTU));
        __shared__ unsigned short tile[64 * 130];
        #pragma unroll 4
        for (int it = 0; it < 32; ++it) {
            int idx = t + 256 * it;
            int c = idx >> 7, h = idx & 127;
            int cg = seg * 64 + c;
            float s = g[cg] * (isV ? 1.f : Wo[h]);
            tile[c * 130 + h] = f2bf(s * W[cg * 128 + h]);
        }
        __syncthreads();
        int h = t >> 1, c0 = (t & 1) * 32;
        for (int cc = 0; cc < 32; cc += 8) {
            unsigned short v[8];
            #pragma unroll
            for (int e = 0; e < 8; ++e) v[e] = tile[(c0 + cc + e) * 130 + h];
            store8(&wt[h * 384 + seg * 64 + c0 + cc], v);
        }
    } else {
        int tt = task - 14;
        bool isK = tt >= 16;
        int seg = isK ? tt - 16 : tt;        // 0..15, 64-col chunk of 1024
        const float* W = isK ? Wk : Wq;
        unsigned short* wt = (unsigned short*)(ws + (isK ? WS_WKT : WS_WQT));
        __shared__ unsigned short tile[64 * 130];
        #pragma unroll 4
        for (int it = 0; it < 32; ++it) {
            int idx = t + 256 * it;
            int c = idx >> 7, h = idx & 127;
            tile[c * 130 + h] = f2bf(W[(size_t)(seg * 64 + c) * 128 + h]);
        }
        __syncthreads();
        int h = t >> 1, c0 = (t & 1) * 32;
        for (int cc = 0; cc < 32; cc += 8) {
            unsigned short v[8];
            #pragma unroll
            for (int e = 0; e < 8; ++e) v[e] = tile[(c0 + cc + e) * 130 + h];
            store8(&wt[h * 1024 + seg * 64 + c0 + cc], v);
        }
    }
}

// ---------------- kernel 2: MFMA projection + stats + P/R (R20: 512 thr) ---
// 256 blocks x 512 thr / 8 waves; 8 rows/block (blocks 0..127: Q, rest: K).
// Wave w owns h-cols [w*16, w*16+16) for main proj; P/R: uv=w&1, nh=w>>1.
// m-tile rows 8..15 never staged/stored (garbage rows never read).
#define XST 1028   // staged-row stride (shorts)
#define QST 132    // qpL stride (shorts)
__global__ __launch_bounds__(512, 2)
void k_proj(const float* __restrict__ Q, const float* __restrict__ K,
            float* __restrict__ ws) {
    int blk = blockIdx.x, t = threadIdx.x;
    bool isK = blk >= 128;
    int r0 = (blk & 127) * 8;
    const float* src = isK ? K : Q;
    const unsigned short* wtin = (const unsigned short*)(ws + (isK ? WS_WKT : WS_WQT));
    float* dst = ws + (isK ? WS_KP : WS_QP);
    int L = t & 63, w = t >> 6;          // 8 waves
    int col = L & 15, quad = L >> 4;
    int h = w * 16 + col;                // this wave's h-column

    __shared__ unsigned short XLb[16 * XST];
    __shared__ unsigned short qpL[16 * QST];
    __shared__ float sp1[16][8], sp2[16][8];

    {   // stage 8 rows x 1024 d as bf16: 512 thr x 16 cols (exact coverage)
        int srow = t >> 6;               // 0..7
        int c0 = (t & 63) * 16;
        const float* sp = src + (size_t)(r0 + srow) * 1024 + c0;
        unsigned pk[8];
        #pragma unroll
        for (int e4 = 0; e4 < 4; ++e4) {
            float4 xv = *(const float4*)(sp + e4 * 4);
            pk[e4 * 2]     = pack_bf2(xv.x, xv.y);
            pk[e4 * 2 + 1] = pack_bf2(xv.z, xv.w);
        }
        unsigned* xp = (unsigned*)&XLb[srow * XST + c0];
        *(uint4*)&xp[0] = *(uint4*)&pk[0];
        *(uint4*)&xp[4] = *(uint4*)&pk[4];
    }
    __syncthreads();

    f32x4 acc = (f32x4){0.f, 0.f, 0.f, 0.f};
    #pragma unroll 4
    for (int ks = 0; ks < 32; ++ks) {
        short8 a = *(const short8*)&XLb[col * XST + ks * 32 + quad * 8];
        short8 b = *(const short8*)&wtin[(size_t)h * 1024 + ks * 32 + quad * 8];
        acc = __builtin_amdgcn_mfma_f32_16x16x32_bf16(a, b, acc, 0, 0, 0);
    }

    #pragma unroll
    for (int r = 0; r < 4; ++r) {
        int row = quad * 4 + r;
        float s1 = acc[r];
        float s2 = acc[r] * acc[r];
        #pragma unroll
        for (int d = 1; d < 16; d <<= 1) { s1 += __shfl_xor(s1, d); s2 += __shfl_xor(s2, d); }
        if (col == 0) { sp1[row][w] = s1; sp2[row][w] = s2; }
        qpL[row * QST + h] = f2bf(acc[r]);
        if (row < 8) dst[(size_t)(r0 + row) * 128 + h] = acc[r];
    }
    __syncthreads();
    if (t < 8) {
        float a1 = 0.f, a2 = 0.f;
        #pragma unroll
        for (int e = 0; e < 8; ++e) { a1 += sp1[t][e]; a2 += sp2[t][e]; }
        ws[(isK ? WS_SK : WS_SQ) + r0 + t] = a1;
        ws[(isK ? WS_KK : WS_QQ) + r0 + t] = a2;
    }

    int uv = w & 1, nh = w >> 1;         // 8 waves: u/v x 4 h-quarters
    const unsigned short* wt = (const unsigned short*)(ws + (uv ? WS_WTV : WS_WTU));
    int cb0 = isK ? 128 : 0;
    f32x4 pacc[2];
    pacc[0] = (f32x4){0.f, 0.f, 0.f, 0.f};
    pacc[1] = (f32x4){0.f, 0.f, 0.f, 0.f};
    #pragma unroll
    for (int ks = 0; ks < 4; ++ks) {
        short8 a = *(const short8*)&qpL[col * QST + ks * 32 + quad * 8];
        #pragma unroll
        for (int nt = 0; nt < 2; ++nt) {
            int hh = nh * 32 + nt * 16 + col;
            short8 b = *(const short8*)&wt[hh * 384 + cb0 + ks * 32 + quad * 8];
            pacc[nt] = __builtin_amdgcn_mfma_f32_16x16x32_bf16(a, b, pacc[nt], 0, 0, 0);
        }
    }
    float* PO = ws + (uv ? (isK ? WS_RV : WS_PV) : (isK ? WS_RU : WS_PU));
    #pragma unroll
    for (int nt = 0; nt < 2; ++nt)
        #pragma unroll
        for (int r = 0; r < 4; ++r) {
            int row = quad * 4 + r;
            if (row < 8)
                PO[(size_t)(r0 + row) * 128 + nh * 32 + nt * 16 + col] = pacc[nt][r];
        }
}

// ---------------- kernel 3: MFMA main (R23: i-group 32, grid 512) ----------
// grid 512 = 2 b x 16 i-groups(32 i) x 16 j-tiles; 512 thr / 8 waves; wave w
// owns h-cols [w*16, w*16+16). 1 barrier/iter, dual dbuf (Alds + red2).
#define ASTR 152   // bf16 A stride: 76 dw ≡ 12 mod 32, 16B-aligned
#define REDS 132   // red2 row stride (floats), 128 entries/row
#define PST  136   // prologue q/q2/k/k2 tile stride (shorts)
// LDS layout (bytes):
//   Alds0 @0 (9728) | Alds1 @9728 (9728) | red2_0 @19456 (16896)
//   red2_1 @36352 (16896) | rsL2 @53248 (8192)  — total 61440
//   prolog (pre-P2 only, unioned into [0,36352)): QL@0 8704; Q2L@8704;
//   KL@17408 8704; K2L@26112 8704  (34816 <= 36352)
__global__ __launch_bounds__(512, 4)
void k_main(const float* __restrict__ ws, float* __restrict__ out,
            const float* __restrict__ Wo, const float* __restrict__ bo) {
    int blk = blockIdx.x;
    int jt = blk & 15, ig = (blk >> 4) & 15, b = blk >> 8;
    int t = threadIdx.x;
    int L = t & 63, w = t >> 6;          // 8 waves
    int col = L & 15, quad = L >> 4;
    int krow0 = b * 512 + jt * 32;
    int jj = t >> 4, cb = (t & 15) * 8;  // staging: row jj, c-range [cb, cb+8)
    int h = w * 16 + col;                // this wave's h-column

    __shared__ __align__(16) char smem[61440];
    unsigned short* Alds0 = (unsigned short*)smem;
    unsigned short* Alds1 = (unsigned short*)(smem + 9728);
    float*          red20 = (float*)(smem + 19456);
    float*          red21 = (float*)(smem + 36352);
    unsigned short* QL    = (unsigned short*)smem;
    unsigned short* Q2L   = (unsigned short*)(smem + 8704);
    unsigned short* KL    = (unsigned short*)(smem + 17408);
    unsigned short* K2L   = (unsigned short*)(smem + 26112);
    float*          rsL2  = (float*)(smem + 53248);

    int bi0 = b * 512 + ig * 32;

    // ---- block-invariant staging ----
    float kreg[8];
    {
        const float* kp = ws + WS_KP + (size_t)(krow0 + jj) * 128 + cb;
        #pragma unroll
        for (int e = 0; e < 8; ++e) kreg[e] = kp[e];
        // bf16 k and k^2 tiles for the stats MFMA
        unsigned kk4[4], k2[4];
        #pragma unroll
        for (int e = 0; e < 4; ++e) {
            kk4[e] = pack_bf2(kreg[e * 2], kreg[e * 2 + 1]);
            k2[e]  = pack_bf2(kreg[e * 2] * kreg[e * 2], kreg[e * 2 + 1] * kreg[e * 2 + 1]);
        }
        *(uint4*)&KL[jj * PST + cb]  = *(uint4*)&kk4[0];
        *(uint4*)&K2L[jj * PST + cb] = *(uint4*)&k2[0];
    }
    {   // q and q^2 tiles: 32 i-rows x 128 c (16 thr/row x 8 cols)
        int row = t >> 4, c0 = (t & 15) * 8;
        const float* qp = ws + WS_QP + (size_t)(bi0 + row) * 128 + c0;
        float4 qv0 = *(const float4*)(qp);
        float4 qv1 = *(const float4*)(qp + 4);
        unsigned qk[4], sk[4];
        qk[0] = pack_bf2(qv0.x, qv0.y); qk[1] = pack_bf2(qv0.z, qv0.w);
        qk[2] = pack_bf2(qv1.x, qv1.y); qk[3] = pack_bf2(qv1.z, qv1.w);
        sk[0] = pack_bf2(qv0.x * qv0.x, qv0.y * qv0.y);
        sk[1] = pack_bf2(qv0.z * qv0.z, qv0.w * qv0.w);
        sk[2] = pack_bf2(qv1.x * qv1.x, qv1.y * qv1.y);
        sk[3] = pack_bf2(qv1.z * qv1.z, qv1.w * qv1.w);
        *(uint4*)&QL[row * PST + c0]  = *(uint4*)&qk[0];
        *(uint4*)&Q2L[row * PST + c0] = *(uint4*)&sk[0];
    }
    // per-thread (ru,rv) packed registers — block-invariant (jl, h fixed)
    unsigned prR[8];
    #pragma unroll
    for (int mt = 0; mt < 2; ++mt)
        #pragma unroll
        for (int r = 0; r < 4; ++r) {
            int jl = mt * 16 + quad * 4 + r;
            float ru = ws[WS_RU + (size_t)(krow0 + jl) * 128 + h];
            float rv = ws[WS_RV + (size_t)(krow0 + jl) * 128 + h];
            prR[mt * 4 + r] = pack_bf2(ru, rv);
        }

    // W3 fragments (c 256..384 of WT) for this wave's 16 h-cols: 32 VGPRs
    short8 w3f[2][4];
    {
        const unsigned short* wtu = (const unsigned short*)(ws + WS_WTU);
        const unsigned short* wtv = (const unsigned short*)(ws + WS_WTV);
        #pragma unroll
        for (int ks = 0; ks < 4; ++ks) {
            w3f[0][ks] = *(const short8*)&wtu[h * 384 + 256 + ks * 32 + quad * 8];
            w3f[1][ks] = *(const short8*)&wtv[h * 384 + 256 + ks * 32 + quad * 8];
        }
    }
    float wo  = Wo[h];
    float gusv = ws[WS_GUS + h] * wo;
    float cuv  = ws[WS_CU + h] * wo;
    float gvsv = ws[WS_GVS + h];
    float cvv  = ws[WS_CV + h];
    float bo0 = bo[0];

    // ---- hoisted prefetch bases (affine in ii) ----
    const float* qpBase = ws + WS_QP + (size_t)bi0 * 128 + cb;
    const float* puBase = ws + WS_PU + (size_t)bi0 * 128 + h;
    const float* pvBase = ws + WS_PV + (size_t)bi0 * 128 + h;
    float4 qA = *(const float4*)(qpBase);
    float4 qB = *(const float4*)(qpBase + 4);
    float puv = puBase[0];
    float pvv = pvBase[0];
    __syncthreads();                                         // P1: QL/Q2L/KL/K2L ready

    // ---- stats via MFMA: d1 = q@k^T, d2 = q^2@(k^2)^T (waves 0..3) ----
    // wave w: ih = w>>1 (i-half of 32), jh = w&1 (j-half of 32)
    if (w < 4) {
        int ih = w >> 1, jh = w & 1;
        int j = jh * 16 + col;
        f32x4 d1a = (f32x4){0.f, 0.f, 0.f, 0.f};
        f32x4 d2a = (f32x4){0.f, 0.f, 0.f, 0.f};
        #pragma unroll
        for (int ks = 0; ks < 4; ++ks) {
            short8 aq  = *(const short8*)&QL[(ih * 16 + col) * PST + ks * 32 + quad * 8];
            short8 bk  = *(const short8*)&KL[j * PST + ks * 32 + quad * 8];
            d1a = __builtin_amdgcn_mfma_f32_16x16x32_bf16(aq, bk, d1a, 0, 0, 0);
            short8 aq2 = *(const short8*)&Q2L[(ih * 16 + col) * PST + ks * 32 + quad * 8];
            short8 bk2 = *(const short8*)&K2L[j * PST + ks * 32 + quad * 8];
            d2a = __builtin_amdgcn_mfma_f32_16x16x32_bf16(aq2, bk2, d2a, 0, 0, 0);
        }
        float skj = ws[WS_SK + krow0 + j];
        float kkj = ws[WS_KK + krow0 + j];
        #pragma unroll
        for (int r = 0; r < 4; ++r) {
            int i = ih * 16 + quad * 4 + r;
            float mu = (ws[WS_SQ + bi0 + i] + skj + d1a[r]) * (1.0f / 384.0f);
            float e2 = (ws[WS_QQ + bi0 + i] + kkj + d2a[r]) * (1.0f / 384.0f);
            float rs = rsqrtf(e2 - mu * mu + EPSLN);
            *(float2*)&rsL2[(i * 32 + j) * 2] = make_float2(rs, rs * mu);
        }
    }
    __syncthreads();                                         // P2: rsL2 ready; QL/KL free

    #pragma unroll 2
    for (int ii = 0; ii < 32; ++ii) {
        unsigned short* Ap = (ii & 1) ? Alds1 : Alds0;       // compile-time (unroll 2)
        float* Rp = (ii & 1) ? red21 : red20;
        float* Rq = (ii & 1) ? red20 : red21;                // previous iter's buffer
        // ---- issue prefetch ii+1 FIRST (affine; stays in flight over BAR_LDS).
        // ii=31 reads row bi0+32: lands in the adjacent ws region (valid, unused).
        float4 qA2 = *(const float4*)(qpBase + (ii + 1) * 128);
        float4 qB2 = *(const float4*)(qpBase + (ii + 1) * 128 + 4);
        float pu2 = puBase[(ii + 1) * 128];
        float pv2 = pvBase[(ii + 1) * 128];
        // ---- stage A[p] = k ⊙ q_i (bf16) ----
        {
            unsigned pk[4];
            float x0 = kreg[0] * qA.x, x1 = kreg[1] * qA.y;
            float x2 = kreg[2] * qA.z, x3 = kreg[3] * qA.w;
            float y0 = kreg[4] * qB.x, y1 = kreg[5] * qB.y;
            float y2 = kreg[6] * qB.z, y3 = kreg[7] * qB.w;
            pk[0] = pack_bf2(x0, x1); pk[1] = pack_bf2(x2, x3);
            pk[2] = pack_bf2(y0, y1); pk[3] = pack_bf2(y2, y3);
            unsigned* arow = (unsigned*)Ap + jj * (ASTR / 2) + cb / 2;
            *(uint4*)&arow[0] = *(uint4*)&pk[0];
        }
        BAR_LDS();                              // B: A[p] ready; red2[p^1] (epi ii-1) done
        // ---- K-loop: S = A @ W3 via MFMA; C init = pu/pv (folds the adds) ----
        f32x4 acc[2][2];
        #pragma unroll
        for (int mt = 0; mt < 2; ++mt) {
            acc[mt][0] = (f32x4){puv, puv, puv, puv};
            acc[mt][1] = (f32x4){pvv, pvv, pvv, pvv};
        }
        #pragma unroll
        for (int ks = 0; ks < 4; ++ks) {
            short8 a0 = *(const short8*)&Ap[col * ASTR + ks * 32 + quad * 8];
            short8 a1 = *(const short8*)&Ap[(col + 16) * ASTR + ks * 32 + quad * 8];
            acc[0][0] = __builtin_amdgcn_mfma_f32_16x16x32_bf16(a0, w3f[0][ks], acc[0][0], 0, 0, 0);
            acc[0][1] = __builtin_amdgcn_mfma_f32_16x16x32_bf16(a0, w3f[1][ks], acc[0][1], 0, 0, 0);
            acc[1][0] = __builtin_amdgcn_mfma_f32_16x16x32_bf16(a1, w3f[0][ks], acc[1][0], 0, 0, 0);
            acc[1][1] = __builtin_amdgcn_mfma_f32_16x16x32_bf16(a1, w3f[1][ks], acc[1][1], 0, 0, 0);
        }
        // ---- tail for iter ii-1 (reads red2[p^1]; fills MFMA latency shadow) ----
        if (ii > 0 && t < 256) {
            const float4* rr = (const float4*)&Rq[(t >> 3) * REDS];
            int k = t & 7;
            float s = 0.f;
            #pragma unroll
            for (int c4 = 0; c4 < 4; ++c4) {
                float4 x = rr[k + c4 * 8];
                s += (x.x + x.y) + (x.z + x.w);
            }
            s += __shfl_xor(s, 1);
            s += __shfl_xor(s, 2);
            s += __shfl_xor(s, 4);
            if (k == 0)
                out[(size_t)(bi0 + ii - 1) * 512 + jt * 32 + (t >> 3)] = s + bo0;
        }
        // ---- epilogue: u', v, fast-gelu -> red2[p] ----
        #pragma unroll
        for (int mt = 0; mt < 2; ++mt) {
            int jb = mt * 16 + quad * 4;
            float4 s0 = *(const float4*)&rsL2[(ii * 32 + jb) * 2];
            float4 s1 = *(const float4*)&rsL2[(ii * 32 + jb) * 2 + 4];
            #pragma unroll
            for (int r = 0; r < 4; ++r) {
                float rs   = r == 0 ? s0.x : r == 1 ? s0.z : r == 2 ? s1.x : s1.z;
                float rsmu = r == 0 ? s0.y : r == 1 ? s0.w : r == 2 ? s1.y : s1.w;
                int jl = jb + r;
                unsigned pr = prR[mt * 4 + r];
                float su  = acc[mt][0][r] + b2f_lo(pr);      // acc already includes pu
                float u   = fmaf(rs, su, fmaf(-rsmu, gusv, cuv));
                float sv_ = acc[mt][1][r] + b2f_hi(pr);      // acc already includes pv
                float v   = fmaf(rs, sv_, fmaf(-rsmu, gvsv, cvv));
                Rp[jl * REDS + w * 16 + col] = u * fast_gelu(v);
            }
        }
        // rotate prefetched state (renamed away by unroll 2)
        qA = qA2; qB = qB2; puv = pu2; pvv = pv2;
    }
    // ---- peeled final tail (iter 31, red2[1]) ----
    BAR_LDS();
    if (t < 256) {
        const float4* rr = (const float4*)&red21[(t >> 3) * REDS];
        int k = t & 7;
        float s = 0.f;
        #pragma unroll
        for (int c4 = 0; c4 < 4; ++c4) {
            float4 x = rr[k + c4 * 8];
            s += (x.x + x.y) + (x.z + x.w);
        }
        s += __shfl_xor(s, 1);
        s += __shfl_xor(s, 2);
        s += __shfl_xor(s, 4);
        if (k == 0)
            out[(size_t)(bi0 + 31) * 512 + jt * 32 + (t >> 3)] = s + bo0;
    }
}

// ---------------------------------------------------------------------------
extern "C" void kernel_launch(void* const* d_in, const int* in_sizes, int n_in,
                              void* d_out, int out_size, void* d_ws, size_t ws_size,
                              hipStream_t stream) {
    const float* Q   = (const float*)d_in[0];
    const float* K   = (const float*)d_in[1];
    const float* Wq  = (const float*)d_in[2];
    const float* Wk  = (const float*)d_in[3];
    const float* g   = (const float*)d_in[4];
    const float* bln = (const float*)d_in[5];
    const float* Wu  = (const float*)d_in[6];
    const float* bu  = (const float*)d_in[7];
    const float* Wv  = (const float*)d_in[8];
    const float* bv  = (const float*)d_in[9];
    const float* Wo  = (const float*)d_in[10];
    const float* bo  = (const float*)d_in[11];
    float* ws  = (float*)d_ws;
    float* out = (float*)d_out;

    hipLaunchKernelGGL(k_prep, dim3(46), dim3(256), 0, stream, Wu, bu, Wv, bv, g, bln, Wo, Wq, Wk, ws);
    hipLaunchKernelGGL(k_proj, dim3(256), dim3(512), 0, stream, Q, K, ws);
    hipLaunchKernelGGL(k_main, dim3(512), dim3(512), 0, stream, ws, out, Wo, bo);
}